// Round 5
// baseline (2798.055 us; speedup 1.0000x reference)
//
#include <hip/hip_runtime.h>

// Model dims
#define T_ 64
#define B_ 1024
#define V_ 128
#define H_ 512

typedef short bf16x8 __attribute__((ext_vector_type(8)));
typedef float f32x4 __attribute__((ext_vector_type(4)));

__device__ __forceinline__ unsigned short f2bf(float f) {
    union { float f; unsigned int i; } v; v.f = f;
    unsigned int x = v.i;
    return (unsigned short)((x + 0x7FFFu + ((x >> 16) & 1u)) >> 16);
}
__device__ __forceinline__ float bf2f(unsigned short u) {
    union { unsigned int i; float f; } v; v.i = ((unsigned int)u) << 16; return v.f;
}
__device__ __forceinline__ float sigm(float x) { return 1.f / (1.f + __expf(-x)); }
__device__ __forceinline__ float tanh_fast(float x) {
    float ax = fabsf(x);
    float t = 1.f - 2.f / (__expf(2.f * ax) + 1.f);   // saturates to 1 on overflow
    return copysignf(t, x);
}

// ---------------- cbias = xh_b + hh_b; zero barrier counters ----------------
__global__ __launch_bounds__(256) void cbias_k(const float* __restrict__ xh_b,
                                               const float* __restrict__ hh_b,
                                               float* __restrict__ cbias,
                                               unsigned int* __restrict__ ctr) {
    int i = blockIdx.x * 256 + threadIdx.x;          // 2048
    cbias[i] = xh_b[i] + hh_b[i];
    if (i < 8) ctr[i] = 0u;
}

// ---------------- convert inp fp32 -> bf16 ----------------
__global__ __launch_bounds__(256) void convx_k(const float* __restrict__ x,
                                               unsigned short* __restrict__ xbf) {
    int i = blockIdx.x * 256 + threadIdx.x;          // T*B*V = 8388608
    xbf[i] = f2bf(x[i]);
}

// ---------------- build Wt bf16 [2048][640]: Wt[n][k] = W[k][n] ----------------
__global__ __launch_bounds__(256) void convw_k(const float* __restrict__ xw,
                                               const float* __restrict__ hw,
                                               unsigned short* __restrict__ wt) {
    int i = blockIdx.x * 256 + threadIdx.x;          // 2048*640 = 1310720
    int n = i / 640, k = i - n * 640;
    float v = (k < 128) ? xw[k * 2048 + n] : hw[(k - 128) * 2048 + n];
    wt[i] = f2bf(v);
}

// ---------------- build Wo bf16 [128][512]: Wo[n][k] = out_w[k][n] ----------------
__global__ __launch_bounds__(256) void convow_k(const float* __restrict__ ow,
                                                unsigned short* __restrict__ wo) {
    int i = blockIdx.x * 256 + threadIdx.x;          // 128*512 = 65536
    int n = i >> 9, k = i & 511;
    wo[i] = f2bf(ow[k * 128 + n]);
}

// ---------------- conv1 3x3 pad1 + relu + 2x2 maxpool ----------------
__global__ __launch_bounds__(256) void conv1_k(const float* __restrict__ img,
                                               const float* __restrict__ w,
                                               const float* __restrict__ bias,
                                               float* __restrict__ out) {
    int id = blockIdx.x * 256 + threadIdx.x;         // B*8*32*32 = 8388608
    int px = id & 31, py = (id >> 5) & 31, oc = (id >> 10) & 7, b = id >> 13;
    const float* ip = img + b * 4096;
    float wv[9];
#pragma unroll
    for (int t = 0; t < 9; ++t) wv[t] = w[oc * 9 + t];
    float bs = bias[oc];
    float m = -3.4e38f;
#pragma unroll
    for (int sy = 0; sy < 2; ++sy)
#pragma unroll
    for (int sx = 0; sx < 2; ++sx) {
        int oy = 2 * py + sy, ox = 2 * px + sx;
        float acc = bs;
#pragma unroll
        for (int ky = 0; ky < 3; ++ky) {
            int iy = oy + ky - 1;
            if (iy < 0 || iy > 63) continue;
#pragma unroll
            for (int kx = 0; kx < 3; ++kx) {
                int ix = ox + kx - 1;
                if (ix < 0 || ix > 63) continue;
                acc += ip[iy * 64 + ix] * wv[ky * 3 + kx];
            }
        }
        m = fmaxf(m, acc);
    }
    out[id] = fmaxf(m, 0.f);
}

// ---------------- conv2 5x5 pad1 + relu + 2x2 maxpool ----------------
__device__ __forceinline__ int c2idx(int ic, int y, int x) {
    return ((ic * 34 + y) * 2 + (x & 1)) * 18 + (x >> 1);
}
__global__ __launch_bounds__(256) void conv2_k(const float* __restrict__ in,
                                               const float* __restrict__ w,
                                               const float* __restrict__ bias,
                                               float* __restrict__ feat) {
    __shared__ float in_s[8 * 34 * 36];
    __shared__ float w_s[3200];
    __shared__ float b_s[16];
    int tid = threadIdx.x, b = blockIdx.x;
    for (int e = tid; e < 8 * 34 * 34; e += 256) {
        int ic = e / 1156, r = e - ic * 1156;
        int y = r / 34, xx = r - y * 34;
        float v = 0.f;
        if (y >= 1 && y <= 32 && xx >= 1 && xx <= 32)
            v = in[b * 8192 + ic * 1024 + (y - 1) * 32 + (xx - 1)];
        in_s[c2idx(ic, y, xx)] = v;
    }
    for (int e = tid; e < 3200; e += 256) w_s[e] = w[e];
    if (tid < 16) b_s[tid] = bias[tid];
    __syncthreads();
    for (int o = tid; o < 3600; o += 256) {
        int oc = o / 225, p = o - oc * 225;
        int py = p / 15, px = p - py * 15;
        float a00, a01, a10, a11;
        a00 = a01 = a10 = a11 = b_s[oc];
        for (int ic = 0; ic < 8; ++ic) {
            const float* wp = w_s + (oc * 8 + ic) * 25;
#pragma unroll
            for (int ky = 0; ky < 5; ++ky) {
                int y0 = 2 * py + ky;
                float r0[6], r1[6];
#pragma unroll
                for (int xx = 0; xx < 6; ++xx) {
                    r0[xx] = in_s[c2idx(ic, y0,     2 * px + xx)];
                    r1[xx] = in_s[c2idx(ic, y0 + 1, 2 * px + xx)];
                }
#pragma unroll
                for (int kx = 0; kx < 5; ++kx) {
                    float wv = wp[ky * 5 + kx];
                    a00 += r0[kx    ] * wv;
                    a01 += r0[kx + 1] * wv;
                    a10 += r1[kx    ] * wv;
                    a11 += r1[kx + 1] * wv;
                }
            }
        }
        float mx = fmaxf(fmaxf(a00, a01), fmaxf(a10, a11));
        feat[b * 3600 + o] = fmaxf(mx, 0.f);
    }
}

// ---------------- imgfc: e = relu(feat @ W + b), M=1024 N=512 K=3600 ----------------
__global__ __launch_bounds__(256) void imgfc_gemm(const float* __restrict__ A,
                                                  const float* __restrict__ W,
                                                  const float* __restrict__ bias,
                                                  float* __restrict__ E) {
    __shared__ __align__(16) float As[16][68];
    __shared__ __align__(16) float Bs[16][68];
    const int tid = threadIdx.x;
    const int tx = tid & 15, ty = tid >> 4;
    const int row0 = blockIdx.y * 64, col0 = blockIdx.x * 64;
    const int am = tid >> 2, ak = (tid & 3) * 4;
    const int bk = tid >> 4, bn = (tid & 15) * 4;
    float acc[4][4] = {};
    for (int k0 = 0; k0 < 3600; k0 += 16) {
        float4 fa = *(const float4*)(A + (row0 + am) * 3600 + k0 + ak);
        float4 fb = *(const float4*)(W + (k0 + bk) * 512 + col0 + bn);
        __syncthreads();
        As[ak + 0][am] = fa.x; As[ak + 1][am] = fa.y; As[ak + 2][am] = fa.z; As[ak + 3][am] = fa.w;
        Bs[bk][bn + 0] = fb.x; Bs[bk][bn + 1] = fb.y; Bs[bk][bn + 2] = fb.z; Bs[bk][bn + 3] = fb.w;
        __syncthreads();
#pragma unroll
        for (int kk = 0; kk < 16; ++kk) {
            float4 av = *(const float4*)(&As[kk][ty * 4]);
            float4 bv = *(const float4*)(&Bs[kk][tx * 4]);
            float a[4] = {av.x, av.y, av.z, av.w};
            float bb[4] = {bv.x, bv.y, bv.z, bv.w};
#pragma unroll
            for (int i = 0; i < 4; ++i)
#pragma unroll
            for (int j = 0; j < 4; ++j) acc[i][j] += a[i] * bb[j];
        }
    }
#pragma unroll
    for (int i = 0; i < 4; ++i) {
        int r = row0 + ty * 4 + i;
#pragma unroll
        for (int j = 0; j < 4; ++j) {
            int cI = col0 + tx * 4 + j;
            E[r * 512 + cI] = fmaxf(acc[i][j] + bias[cI], 0.f);
        }
    }
}

// ---------------- persistent LSTM: all 64 steps in one dispatch ----------------
// grid = 256 blocks exactly (1/CU): block = (rg, jblk): 128 rows x 16 cols x 4 gates.
// h-part weights in 256 VGPRs/wave, x-part weights in LDS, c-state in registers.
// Sync: per-row-group 32-block barrier via device-scope atomic generation counter.
__global__ __launch_bounds__(256, 1) void lstm_persist(
        const unsigned short* __restrict__ xbf,   // [T,B,128] bf16
        const unsigned short* __restrict__ wt,    // [2048,640] bf16
        const float* __restrict__ cbias,          // [2048]
        const float* __restrict__ eimg,           // [B,512]
        unsigned short* __restrict__ hs,          // [T,B,512] bf16
        unsigned int* __restrict__ ctr) {         // [8]
    __shared__ unsigned short xw_s[64 * 136];     // x-part weights, padded stride
    const int tid = threadIdx.x;
    const int wave = tid >> 6, lane = tid & 63;
    const int quad = lane >> 4, l16 = lane & 15;
    const int jblk = blockIdx.x & 31;
    const int rg = blockIdx.x >> 5;
    const int j0 = jblk * 16;
    const int rowbase = rg * 128 + wave * 16;     // tile0 rows; tile1 = +64

    // one-time: stage x-part weights (64 wt-rows x 128 k) into LDS
    for (int e = tid; e < 64 * 16; e += 256) {
        int r = e >> 4, ck = (e & 15) * 8;
        int g = r >> 4, rr = r & 15;
        *(bf16x8*)(xw_s + r * 136 + ck) =
            *(const bf16x8*)(wt + (size_t)(g * 512 + j0 + rr) * 640 + ck);
    }
    // one-time: h-part weights into registers (64 frags = 256 VGPRs)
    bf16x8 bh[64];
#pragma unroll
    for (int g = 0; g < 4; ++g)
#pragma unroll
        for (int kk = 0; kk < 16; ++kk)
            bh[g * 16 + kk] = *(const bf16x8*)(wt + (size_t)(g * 512 + j0 + l16) * 640
                                               + 128 + kk * 32 + quad * 8);
    const int j = j0 + l16;
    float cb0 = cbias[j], cb1 = cbias[512 + j], cb2 = cbias[1024 + j], cb3 = cbias[1536 + j];
    __syncthreads();

    float cst[2][4];                              // c-state per (tile, reg)
#pragma unroll 1
    for (int t = 0; t < T_; ++t) {
        f32x4 acc[8];
#pragma unroll
        for (int q = 0; q < 8; ++q) acc[q] = (f32x4){0.f, 0.f, 0.f, 0.f};

        const unsigned short* xtp = xbf + (size_t)t * (B_ * V_);
#pragma unroll
        for (int kx = 0; kx < 4; ++kx) {
            bf16x8 a0 = *(const bf16x8*)(xtp + (size_t)(rowbase + l16) * 128 + kx * 32 + quad * 8);
            bf16x8 a1 = *(const bf16x8*)(xtp + (size_t)(rowbase + 64 + l16) * 128 + kx * 32 + quad * 8);
#pragma unroll
            for (int g = 0; g < 4; ++g) {
                bf16x8 b = *(const bf16x8*)(xw_s + (g * 16 + l16) * 136 + kx * 32 + quad * 8);
                acc[g]     = __builtin_amdgcn_mfma_f32_16x16x32_bf16(a0, b, acc[g], 0, 0, 0);
                acc[4 + g] = __builtin_amdgcn_mfma_f32_16x16x32_bf16(a1, b, acc[4 + g], 0, 0, 0);
            }
        }
        if (t > 0) {
            const unsigned short* hp = hs + (size_t)(t - 1) * (B_ * H_);
#pragma unroll
            for (int kk = 0; kk < 16; ++kk) {
                bf16x8 a0 = *(const bf16x8*)(hp + (size_t)(rowbase + l16) * 512 + kk * 32 + quad * 8);
                bf16x8 a1 = *(const bf16x8*)(hp + (size_t)(rowbase + 64 + l16) * 512 + kk * 32 + quad * 8);
#pragma unroll
                for (int g = 0; g < 4; ++g) {
                    acc[g]     = __builtin_amdgcn_mfma_f32_16x16x32_bf16(a0, bh[g * 16 + kk], acc[g], 0, 0, 0);
                    acc[4 + g] = __builtin_amdgcn_mfma_f32_16x16x32_bf16(a1, bh[g * 16 + kk], acc[4 + g], 0, 0, 0);
                }
            }
        }
        // epilogue: C/D layout col=l16, row=quad*4+reg
        unsigned short* ho = hs + (size_t)t * (B_ * H_);
#pragma unroll
        for (int tr = 0; tr < 2; ++tr) {
#pragma unroll
            for (int reg = 0; reg < 4; ++reg) {
                int row = rowbase + tr * 64 + quad * 4 + reg;
                size_t o = (size_t)row * 512 + j;
                float ea = (t == 0) ? eimg[o] : 0.f;
                float iv = sigm(acc[tr * 4 + 0][reg] + cb0 + ea);
                float fv = sigm(acc[tr * 4 + 1][reg] + cb1 + ea);
                float gv = tanh_fast(acc[tr * 4 + 2][reg] + cb2 + ea);
                float ov = sigm(acc[tr * 4 + 3][reg] + cb3 + ea);
                float co = (t == 0) ? 0.f : cst[tr][reg];
                float cn = fv * co + iv * gv;
                float hn = ov * tanh_fast(cn);
                cst[tr][reg] = cn;
                ho[o] = f2bf(hn);
            }
        }
        if (t < T_ - 1) {
            __syncthreads();
            if (tid == 0) {
                __threadfence();
                __hip_atomic_fetch_add(&ctr[rg], 1u, __ATOMIC_ACQ_REL, __HIP_MEMORY_SCOPE_AGENT);
                unsigned int target = 32u * (unsigned int)(t + 1);
                int guard = 0;
                while (__hip_atomic_load(&ctr[rg], __ATOMIC_ACQUIRE, __HIP_MEMORY_SCOPE_AGENT) < target
                       && ++guard < (1 << 30))
                    __builtin_amdgcn_s_sleep(16);
                __threadfence();
            }
            __syncthreads();
        }
    }
}

// ---------------- logits + log_softmax via MFMA ----------------
// M=65536 (T*B), N=128, K=512. Block: 64 rows, 4 waves x 16 rows, N full.
__global__ __launch_bounds__(256, 2) void logits_mfma(
        const unsigned short* __restrict__ hs,    // [65536,512] bf16
        const unsigned short* __restrict__ wo,    // [128][512] bf16, k-major
        const float* __restrict__ ob,             // [128]
        float* __restrict__ out) {                // [65536,128]
    __shared__ unsigned short wos[128 * 264];     // half-K stage (64 KB + pad)
    const int tid = threadIdx.x;
    const int wave = tid >> 6, lane = tid & 63;
    const int quad = lane >> 4, l16 = lane & 15;
    const int row0 = blockIdx.x * 64 + wave * 16;
    f32x4 acc[8];
#pragma unroll
    for (int q = 0; q < 8; ++q) acc[q] = (f32x4){0.f, 0.f, 0.f, 0.f};

    for (int half = 0; half < 2; ++half) {
        __syncthreads();
        for (int e = tid; e < 128 * 32; e += 256) {
            int n = e >> 5, c8 = (e & 31) * 8;
            *(bf16x8*)(wos + n * 264 + c8) = *(const bf16x8*)(wo + n * 512 + half * 256 + c8);
        }
        __syncthreads();
#pragma unroll
        for (int ki = 0; ki < 8; ++ki) {
            bf16x8 a = *(const bf16x8*)(hs + (size_t)(row0 + l16) * 512 + half * 256 + ki * 32 + quad * 8);
#pragma unroll
            for (int tn = 0; tn < 8; ++tn) {
                bf16x8 b = *(const bf16x8*)(wos + (tn * 16 + l16) * 264 + ki * 32 + quad * 8);
                acc[tn] = __builtin_amdgcn_mfma_f32_16x16x32_bf16(a, b, acc[tn], 0, 0, 0);
            }
        }
    }
    float bia[8];
#pragma unroll
    for (int tn = 0; tn < 8; ++tn) bia[tn] = ob[tn * 16 + l16];
#pragma unroll
    for (int reg = 0; reg < 4; ++reg) {
        float v[8];
        float m = -3.4e38f;
#pragma unroll
        for (int tn = 0; tn < 8; ++tn) { v[tn] = acc[tn][reg] + bia[tn]; m = fmaxf(m, v[tn]); }
#pragma unroll
        for (int off = 1; off < 16; off <<= 1) m = fmaxf(m, __shfl_xor(m, off, 64));
        float s = 0.f;
#pragma unroll
        for (int tn = 0; tn < 8; ++tn) s += __expf(v[tn] - m);
#pragma unroll
        for (int off = 1; off < 16; off <<= 1) s += __shfl_xor(s, off, 64);
        float z = m + __logf(s);
        int row = row0 + quad * 4 + reg;
        float* op = out + (size_t)row * 128;
#pragma unroll
        for (int tn = 0; tn < 8; ++tn) op[tn * 16 + l16] = v[tn] - z;
    }
}

extern "C" void kernel_launch(void* const* d_in, const int* in_sizes, int n_in,
                              void* d_out, int out_size, void* d_ws, size_t ws_size,
                              hipStream_t stream) {
    const float* inp     = (const float*)d_in[0];
    const float* img     = (const float*)d_in[1];
    const float* conv1_w = (const float*)d_in[2];
    const float* conv1_b = (const float*)d_in[3];
    const float* conv2_w = (const float*)d_in[4];
    const float* conv2_b = (const float*)d_in[5];
    const float* imgfc_w = (const float*)d_in[6];
    const float* imgfc_b = (const float*)d_in[7];
    const float* xh_w    = (const float*)d_in[8];
    const float* xh_b    = (const float*)d_in[9];
    const float* hh_w    = (const float*)d_in[10];
    const float* hh_b    = (const float*)d_in[11];
    const float* out_w   = (const float*)d_in[12];
    const float* out_b   = (const float*)d_in[13];

    // ws layout (~90 MB). conv1out/feat alias the hs region (dead before
    // lstm_persist writes hs[0]).
    char* ws = (char*)d_ws;
    unsigned short* hs  = (unsigned short*)(ws);                   // [0,64M): [T,B,512] bf16
    float* conv1out     = (float*)(ws);                            // [0,32M) alias
    float* feat         = (float*)(ws + (32u << 20));              // [32,46.2M) alias
    float* e            = (float*)(ws + (64u << 20));              // 2 MB
    float* cbias        = (float*)(ws + (66u << 20));              // 8 KB
    unsigned short* xbf = (unsigned short*)(ws + (67u << 20));     // 16 MB
    unsigned short* wt  = (unsigned short*)(ws + (83u << 20));     // 2.56 MB
    unsigned short* wo  = (unsigned short*)(ws + (86u << 20));     // 128 KB
    unsigned int*  ctr  = (unsigned int*)(ws + (87u << 20));       // 32 B
    float* outp         = (float*)d_out;

    cbias_k<<<8, 256, 0, stream>>>(xh_b, hh_b, cbias, ctr);
    convx_k<<<(T_ * B_ * V_) / 256, 256, 0, stream>>>(inp, xbf);
    convw_k<<<(2048 * 640) / 256, 256, 0, stream>>>(xh_w, hh_w, wt);
    convow_k<<<(128 * 512) / 256, 256, 0, stream>>>(out_w, wo);
    conv1_k<<<(B_ * 8 * 32 * 32) / 256, 256, 0, stream>>>(img, conv1_w, conv1_b, conv1out);
    conv2_k<<<B_, 256, 0, stream>>>(conv1out, conv2_w, conv2_b, feat);
    imgfc_gemm<<<dim3(8, 16), 256, 0, stream>>>(feat, imgfc_w, imgfc_b, e);

    lstm_persist<<<256, 256, 0, stream>>>(xbf, wt, cbias, e, hs, ctr);

    logits_mfma<<<(T_ * B_) / 64, 256, 0, stream>>>(hs, wo, out_b, outp);
}

// Round 6
// 1888.303 us; speedup vs baseline: 1.4818x; 1.4818x over previous
//
#include <hip/hip_runtime.h>

// Model dims
#define T_ 64
#define B_ 1024
#define V_ 128
#define H_ 512

typedef short bf16x8 __attribute__((ext_vector_type(8)));
typedef float f32x4 __attribute__((ext_vector_type(4)));

__device__ __forceinline__ unsigned short f2bf(float f) {
    union { float f; unsigned int i; } v; v.f = f;
    unsigned int x = v.i;
    return (unsigned short)((x + 0x7FFFu + ((x >> 16) & 1u)) >> 16);
}
__device__ __forceinline__ float bf2f(unsigned short u) {
    union { unsigned int i; float f; } v; v.i = ((unsigned int)u) << 16; return v.f;
}
__device__ __forceinline__ float sigm(float x) { return 1.f / (1.f + __expf(-x)); }
__device__ __forceinline__ float tanh_fast(float x) {
    float ax = fabsf(x);
    float t = 1.f - 2.f / (__expf(2.f * ax) + 1.f);   // saturates to 1 on overflow
    return copysignf(t, x);
}
// device-visible store of one bf16, write-through to MALL, no cache flush
__device__ __forceinline__ void store_bf16_wt(unsigned short* p, unsigned short v) {
    unsigned int vv = v;
    asm volatile("global_store_short %0, %1, off sc0 sc1" :: "v"(p), "v"(vv) : "memory");
}

// ---------------- cbias = xh_b + hh_b; zero barrier counters ----------------
__global__ __launch_bounds__(256) void cbias_k(const float* __restrict__ xh_b,
                                               const float* __restrict__ hh_b,
                                               float* __restrict__ cbias,
                                               unsigned int* __restrict__ ctr) {
    int i = blockIdx.x * 256 + threadIdx.x;          // 2048
    cbias[i] = xh_b[i] + hh_b[i];
    if (i < 8) ctr[i] = 0u;
}

// ---------------- convert inp fp32 -> bf16 ----------------
__global__ __launch_bounds__(256) void convx_k(const float* __restrict__ x,
                                               unsigned short* __restrict__ xbf) {
    int i = blockIdx.x * 256 + threadIdx.x;          // T*B*V = 8388608
    xbf[i] = f2bf(x[i]);
}

// ---------------- build Wt bf16 [2048][640]: Wt[n][k] = W[k][n] ----------------
__global__ __launch_bounds__(256) void convw_k(const float* __restrict__ xw,
                                               const float* __restrict__ hw,
                                               unsigned short* __restrict__ wt) {
    int i = blockIdx.x * 256 + threadIdx.x;          // 2048*640 = 1310720
    int n = i / 640, k = i - n * 640;
    float v = (k < 128) ? xw[k * 2048 + n] : hw[(k - 128) * 2048 + n];
    wt[i] = f2bf(v);
}

// ---------------- build Wo bf16 [128][512]: Wo[n][k] = out_w[k][n] ----------------
__global__ __launch_bounds__(256) void convow_k(const float* __restrict__ ow,
                                                unsigned short* __restrict__ wo) {
    int i = blockIdx.x * 256 + threadIdx.x;          // 128*512 = 65536
    int n = i >> 9, k = i & 511;
    wo[i] = f2bf(ow[k * 128 + n]);
}

// ---------------- conv1 3x3 pad1 + relu + 2x2 maxpool ----------------
__global__ __launch_bounds__(256) void conv1_k(const float* __restrict__ img,
                                               const float* __restrict__ w,
                                               const float* __restrict__ bias,
                                               float* __restrict__ out) {
    int id = blockIdx.x * 256 + threadIdx.x;         // B*8*32*32 = 8388608
    int px = id & 31, py = (id >> 5) & 31, oc = (id >> 10) & 7, b = id >> 13;
    const float* ip = img + b * 4096;
    float wv[9];
#pragma unroll
    for (int t = 0; t < 9; ++t) wv[t] = w[oc * 9 + t];
    float bs = bias[oc];
    float m = -3.4e38f;
#pragma unroll
    for (int sy = 0; sy < 2; ++sy)
#pragma unroll
    for (int sx = 0; sx < 2; ++sx) {
        int oy = 2 * py + sy, ox = 2 * px + sx;
        float acc = bs;
#pragma unroll
        for (int ky = 0; ky < 3; ++ky) {
            int iy = oy + ky - 1;
            if (iy < 0 || iy > 63) continue;
#pragma unroll
            for (int kx = 0; kx < 3; ++kx) {
                int ix = ox + kx - 1;
                if (ix < 0 || ix > 63) continue;
                acc += ip[iy * 64 + ix] * wv[ky * 3 + kx];
            }
        }
        m = fmaxf(m, acc);
    }
    out[id] = fmaxf(m, 0.f);
}

// ---------------- conv2 5x5 pad1 + relu + 2x2 maxpool ----------------
__device__ __forceinline__ int c2idx(int ic, int y, int x) {
    return ((ic * 34 + y) * 2 + (x & 1)) * 18 + (x >> 1);
}
__global__ __launch_bounds__(256) void conv2_k(const float* __restrict__ in,
                                               const float* __restrict__ w,
                                               const float* __restrict__ bias,
                                               float* __restrict__ feat) {
    __shared__ float in_s[8 * 34 * 36];
    __shared__ float w_s[3200];
    __shared__ float b_s[16];
    int tid = threadIdx.x, b = blockIdx.x;
    for (int e = tid; e < 8 * 34 * 34; e += 256) {
        int ic = e / 1156, r = e - ic * 1156;
        int y = r / 34, xx = r - y * 34;
        float v = 0.f;
        if (y >= 1 && y <= 32 && xx >= 1 && xx <= 32)
            v = in[b * 8192 + ic * 1024 + (y - 1) * 32 + (xx - 1)];
        in_s[c2idx(ic, y, xx)] = v;
    }
    for (int e = tid; e < 3200; e += 256) w_s[e] = w[e];
    if (tid < 16) b_s[tid] = bias[tid];
    __syncthreads();
    for (int o = tid; o < 3600; o += 256) {
        int oc = o / 225, p = o - oc * 225;
        int py = p / 15, px = p - py * 15;
        float a00, a01, a10, a11;
        a00 = a01 = a10 = a11 = b_s[oc];
        for (int ic = 0; ic < 8; ++ic) {
            const float* wp = w_s + (oc * 8 + ic) * 25;
#pragma unroll
            for (int ky = 0; ky < 5; ++ky) {
                int y0 = 2 * py + ky;
                float r0[6], r1[6];
#pragma unroll
                for (int xx = 0; xx < 6; ++xx) {
                    r0[xx] = in_s[c2idx(ic, y0,     2 * px + xx)];
                    r1[xx] = in_s[c2idx(ic, y0 + 1, 2 * px + xx)];
                }
#pragma unroll
                for (int kx = 0; kx < 5; ++kx) {
                    float wv = wp[ky * 5 + kx];
                    a00 += r0[kx    ] * wv;
                    a01 += r0[kx + 1] * wv;
                    a10 += r1[kx    ] * wv;
                    a11 += r1[kx + 1] * wv;
                }
            }
        }
        float mx = fmaxf(fmaxf(a00, a01), fmaxf(a10, a11));
        feat[b * 3600 + o] = fmaxf(mx, 0.f);
    }
}

// ---------------- imgfc: e = relu(feat @ W + b), M=1024 N=512 K=3600 ----------------
__global__ __launch_bounds__(256) void imgfc_gemm(const float* __restrict__ A,
                                                  const float* __restrict__ W,
                                                  const float* __restrict__ bias,
                                                  float* __restrict__ E) {
    __shared__ __align__(16) float As[16][68];
    __shared__ __align__(16) float Bs[16][68];
    const int tid = threadIdx.x;
    const int tx = tid & 15, ty = tid >> 4;
    const int row0 = blockIdx.y * 64, col0 = blockIdx.x * 64;
    const int am = tid >> 2, ak = (tid & 3) * 4;
    const int bk = tid >> 4, bn = (tid & 15) * 4;
    float acc[4][4] = {};
    for (int k0 = 0; k0 < 3600; k0 += 16) {
        float4 fa = *(const float4*)(A + (row0 + am) * 3600 + k0 + ak);
        float4 fb = *(const float4*)(W + (k0 + bk) * 512 + col0 + bn);
        __syncthreads();
        As[ak + 0][am] = fa.x; As[ak + 1][am] = fa.y; As[ak + 2][am] = fa.z; As[ak + 3][am] = fa.w;
        Bs[bk][bn + 0] = fb.x; Bs[bk][bn + 1] = fb.y; Bs[bk][bn + 2] = fb.z; Bs[bk][bn + 3] = fb.w;
        __syncthreads();
#pragma unroll
        for (int kk = 0; kk < 16; ++kk) {
            float4 av = *(const float4*)(&As[kk][ty * 4]);
            float4 bv = *(const float4*)(&Bs[kk][tx * 4]);
            float a[4] = {av.x, av.y, av.z, av.w};
            float bb[4] = {bv.x, bv.y, bv.z, bv.w};
#pragma unroll
            for (int i = 0; i < 4; ++i)
#pragma unroll
            for (int j = 0; j < 4; ++j) acc[i][j] += a[i] * bb[j];
        }
    }
#pragma unroll
    for (int i = 0; i < 4; ++i) {
        int r = row0 + ty * 4 + i;
#pragma unroll
        for (int j = 0; j < 4; ++j) {
            int cI = col0 + tx * 4 + j;
            E[r * 512 + cI] = fmaxf(acc[i][j] + bias[cI], 0.f);
        }
    }
}

// ---------------- persistent LSTM: all 64 steps in one dispatch ----------------
// grid = 256 blocks exactly (1/CU): block = (rg, jblk): 128 rows x 16 cols x 4 gates.
// h-part weights in 256 VGPRs/wave, x-part weights in LDS, c-state in registers.
// Sync: fence-free. hs stores are sc0/sc1 write-through (device-visible, NO L2
// flush); __syncthreads drains vmcnt before the arrive; barrier counter uses
// relaxed agent atomics only. This keeps x/wt/eimg L2-resident across steps.
__global__ __launch_bounds__(256, 1) void lstm_persist(
        const unsigned short* __restrict__ xbf,   // [T,B,128] bf16
        const unsigned short* __restrict__ wt,    // [2048,640] bf16
        const float* __restrict__ cbias,          // [2048]
        const float* __restrict__ eimg,           // [B,512]
        unsigned short* __restrict__ hs,          // [T,B,512] bf16
        unsigned int* __restrict__ ctr) {         // [8]
    __shared__ unsigned short xw_s[64 * 136];     // x-part weights, padded stride
    const int tid = threadIdx.x;
    const int wave = tid >> 6, lane = tid & 63;
    const int quad = lane >> 4, l16 = lane & 15;
    const int jblk = blockIdx.x & 31;
    const int rg = blockIdx.x >> 5;
    const int j0 = jblk * 16;
    const int rowbase = rg * 128 + wave * 16;     // tile0 rows; tile1 = +64

    // one-time: stage x-part weights (64 wt-rows x 128 k) into LDS
    for (int e = tid; e < 64 * 16; e += 256) {
        int r = e >> 4, ck = (e & 15) * 8;
        int g = r >> 4, rr = r & 15;
        *(bf16x8*)(xw_s + r * 136 + ck) =
            *(const bf16x8*)(wt + (size_t)(g * 512 + j0 + rr) * 640 + ck);
    }
    // one-time: h-part weights into registers (64 frags = 256 VGPRs)
    bf16x8 bh[64];
#pragma unroll
    for (int g = 0; g < 4; ++g)
#pragma unroll
        for (int kk = 0; kk < 16; ++kk)
            bh[g * 16 + kk] = *(const bf16x8*)(wt + (size_t)(g * 512 + j0 + l16) * 640
                                               + 128 + kk * 32 + quad * 8);
    const int j = j0 + l16;
    float cb0 = cbias[j], cb1 = cbias[512 + j], cb2 = cbias[1024 + j], cb3 = cbias[1536 + j];
    __syncthreads();

    float cst[2][4];                              // c-state per (tile, reg)
#pragma unroll 1
    for (int t = 0; t < T_; ++t) {
        f32x4 acc[8];
#pragma unroll
        for (int q = 0; q < 8; ++q) acc[q] = (f32x4){0.f, 0.f, 0.f, 0.f};

        const unsigned short* xtp = xbf + (size_t)t * (B_ * V_);
#pragma unroll
        for (int kx = 0; kx < 4; ++kx) {
            bf16x8 a0 = *(const bf16x8*)(xtp + (size_t)(rowbase + l16) * 128 + kx * 32 + quad * 8);
            bf16x8 a1 = *(const bf16x8*)(xtp + (size_t)(rowbase + 64 + l16) * 128 + kx * 32 + quad * 8);
#pragma unroll
            for (int g = 0; g < 4; ++g) {
                bf16x8 b = *(const bf16x8*)(xw_s + (g * 16 + l16) * 136 + kx * 32 + quad * 8);
                acc[g]     = __builtin_amdgcn_mfma_f32_16x16x32_bf16(a0, b, acc[g], 0, 0, 0);
                acc[4 + g] = __builtin_amdgcn_mfma_f32_16x16x32_bf16(a1, b, acc[4 + g], 0, 0, 0);
            }
        }
        if (t > 0) {
            const unsigned short* hp = hs + (size_t)(t - 1) * (B_ * H_);
#pragma unroll
            for (int kk = 0; kk < 16; ++kk) {
                bf16x8 a0 = *(const bf16x8*)(hp + (size_t)(rowbase + l16) * 512 + kk * 32 + quad * 8);
                bf16x8 a1 = *(const bf16x8*)(hp + (size_t)(rowbase + 64 + l16) * 512 + kk * 32 + quad * 8);
#pragma unroll
                for (int g = 0; g < 4; ++g) {
                    acc[g]     = __builtin_amdgcn_mfma_f32_16x16x32_bf16(a0, bh[g * 16 + kk], acc[g], 0, 0, 0);
                    acc[4 + g] = __builtin_amdgcn_mfma_f32_16x16x32_bf16(a1, bh[g * 16 + kk], acc[4 + g], 0, 0, 0);
                }
            }
        }
        // epilogue: C/D layout col=l16, row=quad*4+reg
        unsigned short* ho = hs + (size_t)t * (B_ * H_);
#pragma unroll
        for (int tr = 0; tr < 2; ++tr) {
#pragma unroll
            for (int reg = 0; reg < 4; ++reg) {
                int row = rowbase + tr * 64 + quad * 4 + reg;
                size_t o = (size_t)row * 512 + j;
                float ea = (t == 0) ? eimg[o] : 0.f;
                float iv = sigm(acc[tr * 4 + 0][reg] + cb0 + ea);
                float fv = sigm(acc[tr * 4 + 1][reg] + cb1 + ea);
                float gv = tanh_fast(acc[tr * 4 + 2][reg] + cb2 + ea);
                float ov = sigm(acc[tr * 4 + 3][reg] + cb3 + ea);
                float co = (t == 0) ? 0.f : cst[tr][reg];
                float cn = fv * co + iv * gv;
                float hn = ov * tanh_fast(cn);
                cst[tr][reg] = cn;
                store_bf16_wt(ho + o, f2bf(hn));
            }
        }
        if (t < T_ - 1) {
            __syncthreads();                       // drains each wave's vmcnt (stores acked)
            if (tid == 0) {
                __hip_atomic_fetch_add(&ctr[rg], 1u, __ATOMIC_RELAXED, __HIP_MEMORY_SCOPE_AGENT);
                unsigned int target = 32u * (unsigned int)(t + 1);
                int guard = 0;
                while (__hip_atomic_load(&ctr[rg], __ATOMIC_RELAXED, __HIP_MEMORY_SCOPE_AGENT) < target
                       && ++guard < (1 << 27))
                    __builtin_amdgcn_s_sleep(4);
                asm volatile("" ::: "memory");
            }
            __syncthreads();
        }
    }
}

// ---------------- logits + log_softmax via MFMA ----------------
// M=65536 (T*B), N=128, K=512. Block: 64 rows, 4 waves x 16 rows, N full.
__global__ __launch_bounds__(256, 2) void logits_mfma(
        const unsigned short* __restrict__ hs,    // [65536,512] bf16
        const unsigned short* __restrict__ wo,    // [128][512] bf16, k-major
        const float* __restrict__ ob,             // [128]
        float* __restrict__ out) {                // [65536,128]
    __shared__ unsigned short wos[128 * 264];     // half-K stage (64 KB + pad)
    const int tid = threadIdx.x;
    const int wave = tid >> 6, lane = tid & 63;
    const int quad = lane >> 4, l16 = lane & 15;
    const int row0 = blockIdx.x * 64 + wave * 16;
    f32x4 acc[8];
#pragma unroll
    for (int q = 0; q < 8; ++q) acc[q] = (f32x4){0.f, 0.f, 0.f, 0.f};

    for (int half = 0; half < 2; ++half) {
        __syncthreads();
        for (int e = tid; e < 128 * 32; e += 256) {
            int n = e >> 5, c8 = (e & 31) * 8;
            *(bf16x8*)(wos + n * 264 + c8) = *(const bf16x8*)(wo + n * 512 + half * 256 + c8);
        }
        __syncthreads();
#pragma unroll
        for (int ki = 0; ki < 8; ++ki) {
            bf16x8 a = *(const bf16x8*)(hs + (size_t)(row0 + l16) * 512 + half * 256 + ki * 32 + quad * 8);
#pragma unroll
            for (int tn = 0; tn < 8; ++tn) {
                bf16x8 b = *(const bf16x8*)(wos + (tn * 16 + l16) * 264 + ki * 32 + quad * 8);
                acc[tn] = __builtin_amdgcn_mfma_f32_16x16x32_bf16(a, b, acc[tn], 0, 0, 0);
            }
        }
    }
    float bia[8];
#pragma unroll
    for (int tn = 0; tn < 8; ++tn) bia[tn] = ob[tn * 16 + l16];
#pragma unroll
    for (int reg = 0; reg < 4; ++reg) {
        float v[8];
        float m = -3.4e38f;
#pragma unroll
        for (int tn = 0; tn < 8; ++tn) { v[tn] = acc[tn][reg] + bia[tn]; m = fmaxf(m, v[tn]); }
#pragma unroll
        for (int off = 1; off < 16; off <<= 1) m = fmaxf(m, __shfl_xor(m, off, 64));
        float s = 0.f;
#pragma unroll
        for (int tn = 0; tn < 8; ++tn) s += __expf(v[tn] - m);
#pragma unroll
        for (int off = 1; off < 16; off <<= 1) s += __shfl_xor(s, off, 64);
        float z = m + __logf(s);
        int row = row0 + quad * 4 + reg;
        float* op = out + (size_t)row * 128;
#pragma unroll
        for (int tn = 0; tn < 8; ++tn) op[tn * 16 + l16] = v[tn] - z;
    }
}

extern "C" void kernel_launch(void* const* d_in, const int* in_sizes, int n_in,
                              void* d_out, int out_size, void* d_ws, size_t ws_size,
                              hipStream_t stream) {
    const float* inp     = (const float*)d_in[0];
    const float* img     = (const float*)d_in[1];
    const float* conv1_w = (const float*)d_in[2];
    const float* conv1_b = (const float*)d_in[3];
    const float* conv2_w = (const float*)d_in[4];
    const float* conv2_b = (const float*)d_in[5];
    const float* imgfc_w = (const float*)d_in[6];
    const float* imgfc_b = (const float*)d_in[7];
    const float* xh_w    = (const float*)d_in[8];
    const float* xh_b    = (const float*)d_in[9];
    const float* hh_w    = (const float*)d_in[10];
    const float* hh_b    = (const float*)d_in[11];
    const float* out_w   = (const float*)d_in[12];
    const float* out_b   = (const float*)d_in[13];

    // ws layout (~90 MB). conv1out/feat alias the hs region (dead before
    // lstm_persist writes hs[0]).
    char* ws = (char*)d_ws;
    unsigned short* hs  = (unsigned short*)(ws);                   // [0,64M): [T,B,512] bf16
    float* conv1out     = (float*)(ws);                            // [0,32M) alias
    float* feat         = (float*)(ws + (32u << 20));              // [32,46.2M) alias
    float* e            = (float*)(ws + (64u << 20));              // 2 MB
    float* cbias        = (float*)(ws + (66u << 20));              // 8 KB
    unsigned short* xbf = (unsigned short*)(ws + (67u << 20));     // 16 MB
    unsigned short* wt  = (unsigned short*)(ws + (83u << 20));     // 2.56 MB
    unsigned short* wo  = (unsigned short*)(ws + (86u << 20));     // 128 KB
    unsigned int*  ctr  = (unsigned int*)(ws + (87u << 20));       // 32 B
    float* outp         = (float*)d_out;

    cbias_k<<<8, 256, 0, stream>>>(xh_b, hh_b, cbias, ctr);
    convx_k<<<(T_ * B_ * V_) / 256, 256, 0, stream>>>(inp, xbf);
    convw_k<<<(2048 * 640) / 256, 256, 0, stream>>>(xh_w, hh_w, wt);
    convow_k<<<(128 * 512) / 256, 256, 0, stream>>>(out_w, wo);
    conv1_k<<<(B_ * 8 * 32 * 32) / 256, 256, 0, stream>>>(img, conv1_w, conv1_b, conv1out);
    conv2_k<<<B_, 256, 0, stream>>>(conv1out, conv2_w, conv2_b, feat);
    imgfc_gemm<<<dim3(8, 16), 256, 0, stream>>>(feat, imgfc_w, imgfc_b, e);

    lstm_persist<<<256, 256, 0, stream>>>(xbf, wt, cbias, e, hs, ctr);

    logits_mfma<<<(T_ * B_) / 64, 256, 0, stream>>>(hs, wo, out_b, outp);
}